// Round 1
// baseline (9.565 us; speedup 1.0000x reference)
//
#include <hip/hip_runtime.h>
#include <hip/hip_bf16.h>

// CTPN loss: 4 scalar outputs (loss, cls_loss, v_reg_loss, o_reg_loss).
// Shapes: score/vertical_pred [1,20,512,768] f32, side_refinement [1,10,512,768] f32.
// NP=NN=NO=64, NV=128, NS=128.

#define HH 512
#define WW 768
#define HW (HH * WW)

__device__ __forceinline__ float smooth_l1(float d) {
    float a = fabsf(d);
    return (a < 1.0f) ? 0.5f * d * d : a - 0.5f;
}

__device__ __forceinline__ float wave_reduce_sum(float v) {
    #pragma unroll
    for (int off = 32; off > 0; off >>= 1)
        v += __shfl_down(v, off, 64);
    return v;
}

__global__ __launch_bounds__(256) void ctpn_loss_kernel(
    const float* __restrict__ score,
    const float* __restrict__ vpred,
    const float* __restrict__ side,
    const int* __restrict__ px, const int* __restrict__ py, const int* __restrict__ pa,
    const int* __restrict__ nx, const int* __restrict__ ny, const int* __restrict__ na,
    const int* __restrict__ vx, const int* __restrict__ vy, const int* __restrict__ va,
    const float* __restrict__ vt,
    const int* __restrict__ ox, const int* __restrict__ oy, const int* __restrict__ oa,
    const float* __restrict__ ot,
    float* __restrict__ out)
{
    const int tid = threadIdx.x;
    float cls_part = 0.0f, v_part = 0.0f, o_part = 0.0f;

    if (tid < 64) {
        // positive classification samples: -log_softmax(...)[1]
        int x = px[tid], y = py[tid], a = pa[tid];
        const float* base = score + (size_t)(a * 2) * HW + (size_t)y * WW + x;
        float c0 = base[0];
        float c1 = base[HW];
        float m = fmaxf(c0, c1);
        float lse = m + logf(expf(c0 - m) + expf(c1 - m));
        cls_part = lse - c1;
    } else if (tid < 128) {
        // negative classification samples: -log_softmax(...)[0]
        int i = tid - 64;
        int x = nx[i], y = ny[i], a = na[i];
        const float* base = score + (size_t)(a * 2) * HW + (size_t)y * WW + x;
        float c0 = base[0];
        float c1 = base[HW];
        float m = fmaxf(c0, c1);
        float lse = m + logf(expf(c0 - m) + expf(c1 - m));
        cls_part = lse - c0;
    } else {
        // vertical regression samples (128 of them)
        int i = tid - 128;
        int x = vx[i], y = vy[i], a = va[i];
        const float* base = vpred + (size_t)(a * 2) * HW + (size_t)y * WW + x;
        float p0 = base[0];
        float p1 = base[HW];
        v_part = smooth_l1(p0 - vt[2 * i]) + smooth_l1(p1 - vt[2 * i + 1]);
    }

    if (tid < 64) {
        // side refinement samples (reuse lanes 0..63)
        int x = ox[tid], y = oy[tid], a = oa[tid];
        float p = side[(size_t)a * HW + (size_t)y * WW + x];
        o_part = smooth_l1(p - ot[tid]);
    }

    // reduce the three partial sums across the 256-thread block (4 waves)
    float c = wave_reduce_sum(cls_part);
    float v = wave_reduce_sum(v_part);
    float o = wave_reduce_sum(o_part);

    __shared__ float sc[4], sv[4], so[4];
    const int wid = tid >> 6;
    const int lane = tid & 63;
    if (lane == 0) { sc[wid] = c; sv[wid] = v; so[wid] = o; }
    __syncthreads();

    if (tid == 0) {
        float cs = sc[0] + sc[1] + sc[2] + sc[3];
        float vs = sv[0] + sv[1] + sv[2] + sv[3];
        float os = so[0] + so[1] + so[2] + so[3];
        float cls_loss = cs / 128.0f;           // NS = 128
        float v_reg    = vs / 256.0f;           // NV * 2 elements
        float o_reg    = os / 64.0f;            // NO
        out[0] = cls_loss + v_reg + o_reg;      // loss (LAMBDA1 = LAMBDA2 = 1)
        out[1] = cls_loss;
        out[2] = v_reg;
        out[3] = o_reg;
    }
}

extern "C" void kernel_launch(void* const* d_in, const int* in_sizes, int n_in,
                              void* d_out, int out_size, void* d_ws, size_t ws_size,
                              hipStream_t stream) {
    const float* score = (const float*)d_in[0];
    const float* vpred = (const float*)d_in[1];
    const float* side  = (const float*)d_in[2];
    const int* px = (const int*)d_in[3];
    const int* py = (const int*)d_in[4];
    const int* pa = (const int*)d_in[5];
    const int* nx = (const int*)d_in[6];
    const int* ny = (const int*)d_in[7];
    const int* na = (const int*)d_in[8];
    const int* vx = (const int*)d_in[9];
    const int* vy = (const int*)d_in[10];
    const int* va = (const int*)d_in[11];
    const float* vt = (const float*)d_in[12];
    const int* ox = (const int*)d_in[13];
    const int* oy = (const int*)d_in[14];
    const int* oa = (const int*)d_in[15];
    const float* ot = (const float*)d_in[16];
    float* out = (float*)d_out;

    ctpn_loss_kernel<<<1, 256, 0, stream>>>(
        score, vpred, side,
        px, py, pa, nx, ny, na,
        vx, vy, va, vt,
        ox, oy, oa, ot,
        out);
}